// Round 2
// baseline (317.853 us; speedup 1.0000x reference)
//
#include <hip/hip_runtime.h>
#include <hip/hip_bf16.h>

#define B_  32
#define S_  512
#define D_  768
#define H_  12
#define HD_ 64
#define QKV_ELEMS (B_ * H_ * S_ * HD_)  // 12582912 per tensor

typedef __hip_bfloat16 bf16;
typedef short bf16x8_t __attribute__((ext_vector_type(8)));
typedef float f32x4_t  __attribute__((ext_vector_type(4)));

__device__ __forceinline__ float bf2f(bf16 x) { return __bfloat162float(x); }
__device__ __forceinline__ bf16  f2bf(float x) { return __float2bfloat16(x); }

__device__ __forceinline__ void gl_lds16(const short* g, short* l) {
    __builtin_amdgcn_global_load_lds(
        (const __attribute__((address_space(1))) void*)g,
        (__attribute__((address_space(3))) void*)l, 16, 0, 0);
}

// ---------------------------------------------------------------------------
// fp32 -> bf16 conversion (4 elems/thread)
// ---------------------------------------------------------------------------
__global__ __launch_bounds__(256) void f2bf_kernel(
    const float* __restrict__ in, unsigned short* __restrict__ out, int n4)
{
    int i = blockIdx.x * 256 + threadIdx.x;
    if (i >= n4) return;
    float4 v = reinterpret_cast<const float4*>(in)[i];
    ushort4 o;
    o.x = __bfloat16_as_ushort(f2bf(v.x));
    o.y = __bfloat16_as_ushort(f2bf(v.y));
    o.z = __bfloat16_as_ushort(f2bf(v.z));
    o.w = __bfloat16_as_ushort(f2bf(v.w));
    reinterpret_cast<ushort4*>(out)[i] = o;
}

// ---------------------------------------------------------------------------
// 256x256-tile 8-phase GEMM core (T3+T4+T5 on top of the proven chunk-XOR
// swizzle).  512 threads = 8 waves (2 wr x 4 wc), BK=64, K=768 -> NT=12.
// LDS: 2 x [256][64] bf16 per operand, double-buffered by tile parity
// (128 KiB -> 1 block/CU, 2 waves/SIMD).
//
// LDS row r (128 B = 8 chunks of 16 B) stores global chunk c at slot
// c ^ (r & 7) (pre-swizzled global source; linear gl_lds dest) ->
// fragment ds_read_b128 is bank-conflict-free (measured 0 conflicts).
//
// Phase schedule per K-tile tt (compute buf c = tt&1, other = o):
//   p0: stage A(tt+1) halfB -> o | read all 8 B-frags + A tm0-1 | BAR |
//       prio1 16xMFMA(tm0,1 x tn0-3) prio0 | BAR
//   p1: stage B(tt+2) halfA -> c | read A tm2-3 | BAR | MFMA | BAR
//   p2: stage B(tt+2) halfB -> c | read A tm4-5 | BAR | MFMA | BAR
//   p3: stage A(tt+2) halfA -> c | read A tm6-7 | BAR | MFMA |
//       vmcnt(6) [vmcnt(0) at tt==10] | BAR
// "halfA" of A = rows {0-63, 128-191} (the tm0-3 rows of both wr panels,
// read only at p0/p1); "halfB" = rows {64-127, 192-255} (p2/p3 only);
// B is read only at p0.  Hence every stage lands >=1 barrier after its
// region's last read, and the single counted vmcnt(6)+barrier at p3-end
// guarantees (all-wave) that tile tt+1 is fully resident while 3
// half-tiles (6 loads) stay in flight across the K-tile boundary.
// Raw s_barrier (no vmcnt(0) drain) + empty-asm memory clobbers keep the
// compiler from hoisting LDS reads across phase boundaries.
// ---------------------------------------------------------------------------
#define VM6() asm volatile("s_waitcnt vmcnt(6)" ::: "memory")
#define VM0() asm volatile("s_waitcnt vmcnt(0)" ::: "memory")
#define BAR() do { asm volatile("" ::: "memory"); \
                   __builtin_amdgcn_s_barrier(); \
                   asm volatile("" ::: "memory"); } while (0)

#define STAGE_HALF(Ls, gp, grow0, kcol, hoff) do {                             \
    const int g0_ = (hoff) + w * 8;                                            \
    gl_lds16((gp) + (size_t)((grow0) + g0_ + lrow) * 768 + (kcol) + scol,      \
             (Ls) + g0_ * 64);                                                 \
    const int g1_ = 128 + (hoff) + w * 8;                                      \
    gl_lds16((gp) + (size_t)((grow0) + g1_ + lrow) * 768 + (kcol) + scol,      \
             (Ls) + g1_ * 64);                                                 \
  } while (0)

#define RD_A(i0)                                                               \
    _Pragma("unroll") for (int th = 0; th < 2; ++th)                           \
      _Pragma("unroll") for (int ks = 0; ks < 2; ++ks)                         \
        afr[th][ks] = *(const bf16x8_t*)&As[cb                                 \
            + (wr * 128 + ((i0) * 2 + th) * 16 + l16) * 64                     \
            + (((ks * 4 + quad) ^ (l16 & 7)) * 8)]

#define PH_MFMA(i0)                                                            \
    __builtin_amdgcn_s_setprio(1);                                             \
    _Pragma("unroll") for (int th = 0; th < 2; ++th)                           \
      _Pragma("unroll") for (int tn = 0; tn < 4; ++tn)                         \
        _Pragma("unroll") for (int ks = 0; ks < 2; ++ks)                       \
          acc[(i0) * 2 + th][tn] = __builtin_amdgcn_mfma_f32_16x16x32_bf16(    \
              afr[th][ks], bfr[tn][ks], acc[(i0) * 2 + th][tn], 0, 0, 0);      \
    __builtin_amdgcn_s_setprio(0)

#define GEMM256_CORE(Aptr, Bptr, NBN)                                          \
    __shared__ short As[2 * 256 * 64];  /* 64 KiB */                           \
    __shared__ short Bs[2 * 256 * 64];  /* 64 KiB */                           \
    const int bid = blockIdx.x;                                                \
    /* XCD-aware bijective swizzle (grid % 8 == 0); m-major so each XCD    */  \
    /* chunk reuses A-panels and keeps the whole B operand in its L2.      */  \
    const int swz = (bid & 7) * ((int)gridDim.x >> 3) + (bid >> 3);            \
    const int m0 = (swz / (NBN)) * 256;                                        \
    const int n0 = (swz % (NBN)) * 256;                                        \
    const int t = threadIdx.x;                                                 \
    const int w = t >> 6, lane = t & 63;                                       \
    const int wr = w >> 2, wc = w & 3;                                         \
    const int quad = lane >> 4, l16 = lane & 15;                               \
    const int lrow = lane >> 3;                                                \
    const int scol = ((lane & 7) ^ lrow) * 8;                                  \
    f32x4_t acc[8][4] = {};                                                    \
    /* prologue: tile0 fully, then B1 + A1-halfA (A1-halfB staged at it0 p0)*/ \
    STAGE_HALF(&As[0],     Aptr, m0, 0,  0);                                   \
    STAGE_HALF(&As[0],     Aptr, m0, 0,  64);                                  \
    STAGE_HALF(&Bs[0],     Bptr, n0, 0,  0);                                   \
    STAGE_HALF(&Bs[0],     Bptr, n0, 0,  64);                                  \
    STAGE_HALF(&Bs[16384], Bptr, n0, 64, 0);                                   \
    STAGE_HALF(&Bs[16384], Bptr, n0, 64, 64);                                  \
    STAGE_HALF(&As[16384], Aptr, m0, 64, 0);                                   \
    VM6(); BAR();  /* 14 outstanding -> drains tile0's 8, keeps 6 in flight */ \
    for (int tt = 0; tt < 12; ++tt) {                                          \
      const int cb = (tt & 1) << 14;                                           \
      const int ob = cb ^ 16384;                                               \
      const int kc1 = (tt + 1) << 6, kc2 = (tt + 2) << 6;                      \
      bf16x8_t bfr[4][2], afr[2][2];                                           \
      /* ---- phase 0 ---- */                                                  \
      if (tt < 11) STAGE_HALF(&As[ob], Aptr, m0, kc1, 64);                     \
      _Pragma("unroll") for (int tn = 0; tn < 4; ++tn)                         \
        _Pragma("unroll") for (int ks = 0; ks < 2; ++ks)                       \
          bfr[tn][ks] = *(const bf16x8_t*)&Bs[cb                               \
              + (wc * 64 + tn * 16 + l16) * 64                                 \
              + (((ks * 4 + quad) ^ (l16 & 7)) * 8)];                          \
      RD_A(0);                                                                 \
      BAR(); PH_MFMA(0); BAR();                                                \
      /* ---- phase 1 ---- */                                                  \
      if (tt < 10) STAGE_HALF(&Bs[cb], Bptr, n0, kc2, 0);                      \
      RD_A(1);                                                                 \
      BAR(); PH_MFMA(1); BAR();                                                \
      /* ---- phase 2 ---- */                                                  \
      if (tt < 10) STAGE_HALF(&Bs[cb], Bptr, n0, kc2, 64);                     \
      RD_A(2);                                                                 \
      BAR(); PH_MFMA(2); BAR();                                                \
      /* ---- phase 3 ---- */                                                  \
      if (tt < 10) STAGE_HALF(&As[cb], Aptr, m0, kc2, 0);                      \
      RD_A(3);                                                                 \
      BAR(); PH_MFMA(3);                                                       \
      if (tt == 10) { VM0(); } else if (tt < 10) { VM6(); }                    \
      BAR();                                                                   \
    }

// ---------------------------------------------------------------------------
// Kernel 1: QKV projection -> q/k/v in [B,H,S,HD] bf16
// ---------------------------------------------------------------------------
__global__ __launch_bounds__(512, 2) void qkv_gemm_mfma(
    const short* __restrict__ A, const short* __restrict__ W,
    const float* __restrict__ bias,
    bf16* __restrict__ Q, bf16* __restrict__ Kp, bf16* __restrict__ Vp)
{
    GEMM256_CORE(A, W, 9)

    // n0 is a multiple of 256; 768 = 3*256 so a tile never straddles Q/K/V.
    const int which = n0 / 768;
    const int h = ((n0 % 768) >> 6) + wc;   // wc*64 == one head
    bf16* dst = (which == 0) ? Q : (which == 1) ? Kp : Vp;
    float bv[4];
#pragma unroll
    for (int tn = 0; tn < 4; ++tn) bv[tn] = bias[n0 + wc * 64 + tn * 16 + l16];
#pragma unroll
    for (int tm = 0; tm < 8; ++tm) {
#pragma unroll
        for (int r = 0; r < 4; ++r) {
            int m = m0 + wr * 128 + tm * 16 + quad * 4 + r;
            int b = m >> 9, s = m & 511;
            size_t rb = (((size_t)b * H_ + h) * S_ + s) * HD_;
#pragma unroll
            for (int tn = 0; tn < 4; ++tn)
                dst[rb + tn * 16 + l16] = f2bf(acc[tm][tn][r] + bv[tn]);
        }
    }
}

// ---------------------------------------------------------------------------
// Kernel 3: output projection, fp32 out
// ---------------------------------------------------------------------------
__global__ __launch_bounds__(512, 2) void proj_gemm_mfma(
    const short* __restrict__ A, const short* __restrict__ W,
    const float* __restrict__ bias, float* __restrict__ out)
{
    GEMM256_CORE(A, W, 3)

    float bv[4];
#pragma unroll
    for (int tn = 0; tn < 4; ++tn) bv[tn] = bias[n0 + wc * 64 + tn * 16 + l16];
#pragma unroll
    for (int tm = 0; tm < 8; ++tm) {
#pragma unroll
        for (int r = 0; r < 4; ++r) {
            int m = m0 + wr * 128 + tm * 16 + quad * 4 + r;
#pragma unroll
            for (int tn = 0; tn < 4; ++tn)
                out[(size_t)m * 768 + n0 + wc * 64 + tn * 16 + l16] =
                    acc[tm][tn][r] + bv[tn];
        }
    }
}

// ---------------------------------------------------------------------------
// Kernel 2: MFMA flash attention, swizzled Q/K tiles.  (unchanged)
// ---------------------------------------------------------------------------
#define QT 128
#define KT 64
#define PS 68
#define VS 68

__global__ __launch_bounds__(256, 3) void attn_mfma(
    const short* __restrict__ Qg, const short* __restrict__ Kg,
    const short* __restrict__ Vg, bf16* __restrict__ O)
{
    __shared__ short Qs[QT * 64];     // 16 KB
    __shared__ short Ks[KT * 64];     // 8 KB
    __shared__ short Vt[64 * VS];     // 8.5 KB  [dim][key]
    __shared__ short Ps[QT * PS];     // 17 KB

    const int t = threadIdx.x;
    const int w = t >> 6, lane = t & 63;
    const int quad = lane >> 4, l16 = lane & 15;
    const int lrow = lane >> 3;
    const int scol = (((lane & 7) ^ (lrow & 7)) * 8);
    const int qt = blockIdx.x & 3;
    const int bh = blockIdx.x >> 2;
    const int q0 = qt * QT;
    const size_t base = (size_t)bh * (S_ * HD_);

    // stage Q tile [128 x 64] once (swizzled)
#pragma unroll
    for (int j = 0; j < 4; ++j) {
        int R = j * 32 + w * 8;
        gl_lds16(Qg + base + (size_t)(q0 + R + lrow) * 64 + scol, &Qs[R * 64]);
    }

    const int wq = w * 32;
    f32x4_t Oacc[2][4] = {};
    float lsum[2][4] = {};

    for (int kt = 0; kt < S_; kt += KT) {
        __syncthreads();
        // stage K tile [64 x 64] (swizzled)
#pragma unroll
        for (int j = 0; j < 2; ++j) {
            int R = j * 32 + w * 8;
            gl_lds16(Kg + base + (size_t)(kt + R + lrow) * 64 + scol, &Ks[R * 64]);
        }
        // stage V transposed: Vt[dim][key] (stride 68: reads/writes ~free)
        {
            int k = lane, dg = w;
            const bf16x8_t* gv = (const bf16x8_t*)(Vg + base + (size_t)(kt + k) * 64 + dg * 16);
            bf16x8_t v0 = gv[0], v1 = gv[1];
#pragma unroll
            for (int i = 0; i < 8; ++i) {
                Vt[(dg * 16 + i) * VS + k]     = v0[i];
                Vt[(dg * 16 + 8 + i) * VS + k] = v1[i];
            }
        }
        __syncthreads();

        // QK^T: per-wave S tile [32 queries x 64 keys]
        f32x4_t sc[2][4] = {};
#pragma unroll
        for (int ks = 0; ks < 64; ks += 32) {
            bf16x8_t aq[2], bk[4];
#pragma unroll
            for (int tm = 0; tm < 2; ++tm)
                aq[tm] = *(const bf16x8_t*)&Qs[(wq + tm * 16 + l16) * 64
                        + ((((ks >> 3) + quad) ^ (l16 & 7)) * 8)];
#pragma unroll
            for (int tn = 0; tn < 4; ++tn)
                bk[tn] = *(const bf16x8_t*)&Ks[(tn * 16 + l16) * 64
                        + ((((ks >> 3) + quad) ^ (l16 & 7)) * 8)];
#pragma unroll
            for (int tm = 0; tm < 2; ++tm)
#pragma unroll
                for (int tn = 0; tn < 4; ++tn)
                    sc[tm][tn] = __builtin_amdgcn_mfma_f32_16x16x32_bf16(
                        aq[tm], bk[tn], sc[tm][tn], 0, 0, 0);
        }

        // p = exp(s * 0.125); per-lane row partials; P -> LDS bf16
#pragma unroll
        for (int tm = 0; tm < 2; ++tm) {
#pragma unroll
            for (int r = 0; r < 4; ++r) {
                int row = wq + tm * 16 + quad * 4 + r;
                float rs = 0.f;
#pragma unroll
                for (int tn = 0; tn < 4; ++tn) {
                    float p = __expf(sc[tm][tn][r] * 0.125f);
                    rs += p;
                    Ps[row * PS + tn * 16 + l16] = (short)__bfloat16_as_ushort(f2bf(p));
                }
                lsum[tm][r] += rs;
            }
        }
        // no barrier: Ps rows [wq, wq+32) are written and read by this wave only

        // PV: O[32 x 64] per wave
#pragma unroll
        for (int ks = 0; ks < 64; ks += 32) {
            bf16x8_t ap[2], bv[4];
#pragma unroll
            for (int tm = 0; tm < 2; ++tm)
                ap[tm] = *(const bf16x8_t*)&Ps[(wq + tm * 16 + l16) * PS + ks + quad * 8];
#pragma unroll
            for (int tn = 0; tn < 4; ++tn)
                bv[tn] = *(const bf16x8_t*)&Vt[(tn * 16 + l16) * VS + ks + quad * 8];
#pragma unroll
            for (int tm = 0; tm < 2; ++tm)
#pragma unroll
                for (int tn = 0; tn < 4; ++tn)
                    Oacc[tm][tn] = __builtin_amdgcn_mfma_f32_16x16x32_bf16(
                        ap[tm], bv[tn], Oacc[tm][tn], 0, 0, 0);
        }
    }

    // reduce row sums across 16 col-lanes, normalize, store
    float linv[2][4];
#pragma unroll
    for (int tm = 0; tm < 2; ++tm)
#pragma unroll
        for (int r = 0; r < 4; ++r) {
            float v = lsum[tm][r];
            v += __shfl_xor(v, 1, 64);
            v += __shfl_xor(v, 2, 64);
            v += __shfl_xor(v, 4, 64);
            v += __shfl_xor(v, 8, 64);
            linv[tm][r] = 1.f / v;
        }
    const int b = bh / H_, h = bh % H_;
#pragma unroll
    for (int tm = 0; tm < 2; ++tm) {
#pragma unroll
        for (int r = 0; r < 4; ++r) {
            int row = q0 + wq + tm * 16 + quad * 4 + r;
            size_t ob = ((size_t)b * S_ + row) * D_ + h * HD_;
#pragma unroll
            for (int tn = 0; tn < 4; ++tn)
                O[ob + tn * 16 + l16] = f2bf(Oacc[tm][tn][r] * linv[tm][r]);
        }
    }
}

// ---------------------------------------------------------------------------
extern "C" void kernel_launch(void* const* d_in, const int* in_sizes, int n_in,
                              void* d_out, int out_size, void* d_ws, size_t ws_size,
                              hipStream_t stream) {
    const float* x      = (const float*)d_in[0];
    const float* qkv_w  = (const float*)d_in[1];
    const float* qkv_b  = (const float*)d_in[2];
    const float* proj_w = (const float*)d_in[3];
    const float* proj_b = (const float*)d_in[4];
    float* out = (float*)d_out;

    unsigned short* q     = (unsigned short*)d_ws;
    unsigned short* k     = q + QKV_ELEMS;
    unsigned short* v     = k + QKV_ELEMS;
    unsigned short* slot4 = v + QKV_ELEMS;          // x_bf, then attn-out
    unsigned short* wq    = slot4 + QKV_ELEMS;
    unsigned short* wp    = wq + 2304 * 768;

    f2bf_kernel<<<(16384 * 768 / 4 + 255) / 256, 256, 0, stream>>>(x, slot4, 16384 * 768 / 4);
    f2bf_kernel<<<(2304 * 768 / 4 + 255) / 256, 256, 0, stream>>>(qkv_w, wq, 2304 * 768 / 4);
    f2bf_kernel<<<(768 * 768 / 4 + 255) / 256, 256, 0, stream>>>(proj_w, wp, 768 * 768 / 4);

    // 16384/256 = 64 m-blocks; qkv: 2304/256 = 9 n-blocks; proj: 768/256 = 3
    qkv_gemm_mfma<<<dim3(64 * 9), 512, 0, stream>>>(
        (const short*)slot4, (const short*)wq, qkv_b,
        (bf16*)q, (bf16*)k, (bf16*)v);

    attn_mfma<<<dim3(32 * 12 * 4), 256, 0, stream>>>(
        (const short*)q, (const short*)k, (const short*)v, (bf16*)slot4);

    proj_gemm_mfma<<<dim3(64 * 3), 512, 0, stream>>>(
        (const short*)slot4, (const short*)wp, proj_b, out);
}

// Round 3
// 290.458 us; speedup vs baseline: 1.0943x; 1.0943x over previous
//
#include <hip/hip_runtime.h>
#include <hip/hip_bf16.h>

#define B_  32
#define S_  512
#define D_  768
#define H_  12
#define HD_ 64
#define QKV_ELEMS (B_ * H_ * S_ * HD_)  // 12582912 per tensor

typedef __hip_bfloat16 bf16;
typedef short bf16x8_t __attribute__((ext_vector_type(8)));
typedef float f32x4_t  __attribute__((ext_vector_type(4)));

__device__ __forceinline__ float bf2f(bf16 x) { return __bfloat162float(x); }
__device__ __forceinline__ bf16  f2bf(float x) { return __float2bfloat16(x); }

__device__ __forceinline__ void gl_lds16(const short* g, short* l) {
    __builtin_amdgcn_global_load_lds(
        (const __attribute__((address_space(1))) void*)g,
        (__attribute__((address_space(3))) void*)l, 16, 0, 0);
}

// ---------------------------------------------------------------------------
// fp32 -> bf16 conversion (4 elems/thread)
// ---------------------------------------------------------------------------
__global__ __launch_bounds__(256) void f2bf_kernel(
    const float* __restrict__ in, unsigned short* __restrict__ out, int n4)
{
    int i = blockIdx.x * 256 + threadIdx.x;
    if (i >= n4) return;
    float4 v = reinterpret_cast<const float4*>(in)[i];
    ushort4 o;
    o.x = __bfloat16_as_ushort(f2bf(v.x));
    o.y = __bfloat16_as_ushort(f2bf(v.y));
    o.z = __bfloat16_as_ushort(f2bf(v.z));
    o.w = __bfloat16_as_ushort(f2bf(v.w));
    reinterpret_cast<ushort4*>(out)[i] = o;
}

// ---------------------------------------------------------------------------
// 256x256-tile 8-phase GEMM core.  512 threads = 8 waves (2 wr x 4 wc),
// BK=64, K=768 -> NT=12.  LDS: 2 x [256][64] bf16 per operand (128 KiB).
//
// ROUND-2 FIX: no memory-clobber asm anywhere in the K-loop.  The AMDGPU
// waitcnt pass drains vmcnt(0)+lgkmcnt(0) before any "memory"-clobbering
// inline asm, which round-1's BAR() did 16x per K-tile -> full pipeline
// serialization (MfmaUtil 19%).  m201-exact idiom instead: raw s_barrier,
// clobber-free s_waitcnt asm, counted vmcnt(6) once per K-tile.
//
// LDS row r (128 B = 8 chunks of 16 B) stores global chunk c at slot
// c ^ (r & 7) (pre-swizzled global source; linear gl_lds dest) ->
// fragment ds_read_b128 is bank-conflict-free (measured: 0 conflicts).
//
// Phase schedule per K-tile tt (compute buf c = tt&1, other = o):
//   p0: read 8 B-frags + A tm0-1 | stage A(tt+1) halfB -> o | BAR lgkm0
//       prio1 16xMFMA prio0 | BAR
//   p1: read A tm2-3 | stage B(tt+2) halfA -> c | BAR lgkm0 MFMA | BAR
//   p2: read A tm4-5 | stage B(tt+2) halfB -> c | BAR lgkm0 MFMA | BAR
//   p3: read A tm6-7 | stage A(tt+2) halfA -> c | BAR lgkm0 MFMA |
//       vmcnt(6) [vmcnt(0) at tt==10] | BAR
// "halfA" of A = rows {0-63,128-191} (tm0-3 of both wr panels, read only
// p0/p1); "halfB" = rows {64-127,192-255} (p2/p3); B read only at p0.
// Every stage lands >=1 barrier after its region's last read; the counted
// vmcnt(6)+barrier at p3-end guarantees tile tt+1 fully resident while 3
// half-tiles (6 loads) stay in flight across the K-tile boundary.
// ---------------------------------------------------------------------------
#define VM6()   asm volatile("s_waitcnt vmcnt(6)")
#define VM0()   asm volatile("s_waitcnt vmcnt(0)")
#define LGKM0() asm volatile("s_waitcnt lgkmcnt(0)")
#define BAR()   __builtin_amdgcn_s_barrier()

#define STAGE_HALF(Ls, gp, grow0, kcol, hoff) do {                             \
    const int g0_ = (hoff) + w * 8;                                            \
    gl_lds16((gp) + (size_t)((grow0) + g0_ + lrow) * 768 + (kcol) + scol,      \
             (Ls) + g0_ * 64);                                                 \
    const int g1_ = 128 + (hoff) + w * 8;                                      \
    gl_lds16((gp) + (size_t)((grow0) + g1_ + lrow) * 768 + (kcol) + scol,      \
             (Ls) + g1_ * 64);                                                 \
  } while (0)

#define RD_A(i0)                                                               \
    _Pragma("unroll") for (int th = 0; th < 2; ++th)                           \
      _Pragma("unroll") for (int ks = 0; ks < 2; ++ks)                         \
        afr[th][ks] = *(const bf16x8_t*)&As[cb                                 \
            + (wr * 128 + ((i0) * 2 + th) * 16 + l16) * 64                     \
            + (((ks * 4 + quad) ^ (l16 & 7)) * 8)]

#define PH_MFMA(i0)                                                            \
    __builtin_amdgcn_s_setprio(1);                                             \
    _Pragma("unroll") for (int th = 0; th < 2; ++th)                           \
      _Pragma("unroll") for (int tn = 0; tn < 4; ++tn)                         \
        _Pragma("unroll") for (int ks = 0; ks < 2; ++ks)                       \
          acc[(i0) * 2 + th][tn] = __builtin_amdgcn_mfma_f32_16x16x32_bf16(    \
              afr[th][ks], bfr[tn][ks], acc[(i0) * 2 + th][tn], 0, 0, 0);      \
    __builtin_amdgcn_s_setprio(0)

#define GEMM256_CORE(Aptr, Bptr, NBN)                                          \
    __shared__ short As[2 * 256 * 64];  /* 64 KiB */                           \
    __shared__ short Bs[2 * 256 * 64];  /* 64 KiB */                           \
    const int bid = blockIdx.x;                                                \
    /* XCD-aware bijective swizzle (grid % 8 == 0); m-major so each XCD    */  \
    /* chunk reuses A-panels and keeps the whole B operand in its L2.      */  \
    const int swz = (bid & 7) * ((int)gridDim.x >> 3) + (bid >> 3);            \
    const int m0 = (swz / (NBN)) * 256;                                        \
    const int n0 = (swz % (NBN)) * 256;                                        \
    const int t = threadIdx.x;                                                 \
    const int w = t >> 6, lane = t & 63;                                       \
    const int wr = w >> 2, wc = w & 3;                                         \
    const int quad = lane >> 4, l16 = lane & 15;                               \
    const int lrow = lane >> 3;                                                \
    const int scol = ((lane & 7) ^ lrow) * 8;                                  \
    f32x4_t acc[8][4] = {};                                                    \
    /* prologue: tile0 fully, then B1 + A1-halfA (A1-halfB staged at it0 p0)*/ \
    STAGE_HALF(&As[0],     Aptr, m0, 0,  0);                                   \
    STAGE_HALF(&As[0],     Aptr, m0, 0,  64);                                  \
    STAGE_HALF(&Bs[0],     Bptr, n0, 0,  0);                                   \
    STAGE_HALF(&Bs[0],     Bptr, n0, 0,  64);                                  \
    STAGE_HALF(&Bs[16384], Bptr, n0, 64, 0);                                   \
    STAGE_HALF(&Bs[16384], Bptr, n0, 64, 64);                                  \
    STAGE_HALF(&As[16384], Aptr, m0, 64, 0);                                   \
    VM6(); BAR();  /* 14 outstanding -> drains tile0's 8, keeps 6 in flight */ \
    for (int tt = 0; tt < 12; ++tt) {                                          \
      const int cb = (tt & 1) << 14;                                           \
      const int ob = cb ^ 16384;                                               \
      const int kc1 = (tt + 1) << 6, kc2 = (tt + 2) << 6;                      \
      bf16x8_t bfr[4][2], afr[2][2];                                           \
      /* ---- phase 0 ---- */                                                  \
      _Pragma("unroll") for (int tn = 0; tn < 4; ++tn)                         \
        _Pragma("unroll") for (int ks = 0; ks < 2; ++ks)                       \
          bfr[tn][ks] = *(const bf16x8_t*)&Bs[cb                               \
              + (wc * 64 + tn * 16 + l16) * 64                                 \
              + (((ks * 4 + quad) ^ (l16 & 7)) * 8)];                          \
      RD_A(0);                                                                 \
      if (tt < 11) STAGE_HALF(&As[ob], Aptr, m0, kc1, 64);                     \
      BAR(); LGKM0();                                                          \
      PH_MFMA(0); BAR();                                                       \
      /* ---- phase 1 ---- */                                                  \
      RD_A(1);                                                                 \
      if (tt < 10) STAGE_HALF(&Bs[cb], Bptr, n0, kc2, 0);                      \
      BAR(); LGKM0();                                                          \
      PH_MFMA(1); BAR();                                                       \
      /* ---- phase 2 ---- */                                                  \
      RD_A(2);                                                                 \
      if (tt < 10) STAGE_HALF(&Bs[cb], Bptr, n0, kc2, 64);                     \
      BAR(); LGKM0();                                                          \
      PH_MFMA(2); BAR();                                                       \
      /* ---- phase 3 ---- */                                                  \
      RD_A(3);                                                                 \
      if (tt < 10) STAGE_HALF(&As[cb], Aptr, m0, kc2, 0);                      \
      BAR(); LGKM0();                                                          \
      PH_MFMA(3);                                                              \
      if (tt == 10) { VM0(); } else if (tt < 10) { VM6(); }                    \
      BAR();                                                                   \
    }

// ---------------------------------------------------------------------------
// Kernel 1: QKV projection -> q/k/v in [B,H,S,HD] bf16
// ---------------------------------------------------------------------------
__global__ __launch_bounds__(512, 2) void qkv_gemm_mfma(
    const short* __restrict__ A, const short* __restrict__ W,
    const float* __restrict__ bias,
    bf16* __restrict__ Q, bf16* __restrict__ Kp, bf16* __restrict__ Vp)
{
    GEMM256_CORE(A, W, 9)

    // n0 is a multiple of 256; 768 = 3*256 so a tile never straddles Q/K/V.
    const int which = n0 / 768;
    const int h = ((n0 % 768) >> 6) + wc;   // wc*64 == one head
    bf16* dst = (which == 0) ? Q : (which == 1) ? Kp : Vp;
    float bv[4];
#pragma unroll
    for (int tn = 0; tn < 4; ++tn) bv[tn] = bias[n0 + wc * 64 + tn * 16 + l16];
#pragma unroll
    for (int tm = 0; tm < 8; ++tm) {
#pragma unroll
        for (int r = 0; r < 4; ++r) {
            int m = m0 + wr * 128 + tm * 16 + quad * 4 + r;
            int b = m >> 9, s = m & 511;
            size_t rb = (((size_t)b * H_ + h) * S_ + s) * HD_;
#pragma unroll
            for (int tn = 0; tn < 4; ++tn)
                dst[rb + tn * 16 + l16] = f2bf(acc[tm][tn][r] + bv[tn]);
        }
    }
}

// ---------------------------------------------------------------------------
// Kernel 3: output projection, fp32 out
// ---------------------------------------------------------------------------
__global__ __launch_bounds__(512, 2) void proj_gemm_mfma(
    const short* __restrict__ A, const short* __restrict__ W,
    const float* __restrict__ bias, float* __restrict__ out)
{
    GEMM256_CORE(A, W, 3)

    float bv[4];
#pragma unroll
    for (int tn = 0; tn < 4; ++tn) bv[tn] = bias[n0 + wc * 64 + tn * 16 + l16];
#pragma unroll
    for (int tm = 0; tm < 8; ++tm) {
#pragma unroll
        for (int r = 0; r < 4; ++r) {
            int m = m0 + wr * 128 + tm * 16 + quad * 4 + r;
#pragma unroll
            for (int tn = 0; tn < 4; ++tn)
                out[(size_t)m * 768 + n0 + wc * 64 + tn * 16 + l16] =
                    acc[tm][tn][r] + bv[tn];
        }
    }
}

// ---------------------------------------------------------------------------
// Kernel 2: MFMA flash attention, swizzled Q/K tiles.  (unchanged)
// ---------------------------------------------------------------------------
#define QT 128
#define KT 64
#define PS 68
#define VS 68

__global__ __launch_bounds__(256, 3) void attn_mfma(
    const short* __restrict__ Qg, const short* __restrict__ Kg,
    const short* __restrict__ Vg, bf16* __restrict__ O)
{
    __shared__ short Qs[QT * 64];     // 16 KB
    __shared__ short Ks[KT * 64];     // 8 KB
    __shared__ short Vt[64 * VS];     // 8.5 KB  [dim][key]
    __shared__ short Ps[QT * PS];     // 17 KB

    const int t = threadIdx.x;
    const int w = t >> 6, lane = t & 63;
    const int quad = lane >> 4, l16 = lane & 15;
    const int lrow = lane >> 3;
    const int scol = (((lane & 7) ^ (lrow & 7)) * 8);
    const int qt = blockIdx.x & 3;
    const int bh = blockIdx.x >> 2;
    const int q0 = qt * QT;
    const size_t base = (size_t)bh * (S_ * HD_);

    // stage Q tile [128 x 64] once (swizzled)
#pragma unroll
    for (int j = 0; j < 4; ++j) {
        int R = j * 32 + w * 8;
        gl_lds16(Qg + base + (size_t)(q0 + R + lrow) * 64 + scol, &Qs[R * 64]);
    }

    const int wq = w * 32;
    f32x4_t Oacc[2][4] = {};
    float lsum[2][4] = {};

    for (int kt = 0; kt < S_; kt += KT) {
        __syncthreads();
        // stage K tile [64 x 64] (swizzled)
#pragma unroll
        for (int j = 0; j < 2; ++j) {
            int R = j * 32 + w * 8;
            gl_lds16(Kg + base + (size_t)(kt + R + lrow) * 64 + scol, &Ks[R * 64]);
        }
        // stage V transposed: Vt[dim][key] (stride 68: reads/writes ~free)
        {
            int k = lane, dg = w;
            const bf16x8_t* gv = (const bf16x8_t*)(Vg + base + (size_t)(kt + k) * 64 + dg * 16);
            bf16x8_t v0 = gv[0], v1 = gv[1];
#pragma unroll
            for (int i = 0; i < 8; ++i) {
                Vt[(dg * 16 + i) * VS + k]     = v0[i];
                Vt[(dg * 16 + 8 + i) * VS + k] = v1[i];
            }
        }
        __syncthreads();

        // QK^T: per-wave S tile [32 queries x 64 keys]
        f32x4_t sc[2][4] = {};
#pragma unroll
        for (int ks = 0; ks < 64; ks += 32) {
            bf16x8_t aq[2], bk[4];
#pragma unroll
            for (int tm = 0; tm < 2; ++tm)
                aq[tm] = *(const bf16x8_t*)&Qs[(wq + tm * 16 + l16) * 64
                        + ((((ks >> 3) + quad) ^ (l16 & 7)) * 8)];
#pragma unroll
            for (int tn = 0; tn < 4; ++tn)
                bk[tn] = *(const bf16x8_t*)&Ks[(tn * 16 + l16) * 64
                        + ((((ks >> 3) + quad) ^ (l16 & 7)) * 8)];
#pragma unroll
            for (int tm = 0; tm < 2; ++tm)
#pragma unroll
                for (int tn = 0; tn < 4; ++tn)
                    sc[tm][tn] = __builtin_amdgcn_mfma_f32_16x16x32_bf16(
                        aq[tm], bk[tn], sc[tm][tn], 0, 0, 0);
        }

        // p = exp(s * 0.125); per-lane row partials; P -> LDS bf16
#pragma unroll
        for (int tm = 0; tm < 2; ++tm) {
#pragma unroll
            for (int r = 0; r < 4; ++r) {
                int row = wq + tm * 16 + quad * 4 + r;
                float rs = 0.f;
#pragma unroll
                for (int tn = 0; tn < 4; ++tn) {
                    float p = __expf(sc[tm][tn][r] * 0.125f);
                    rs += p;
                    Ps[row * PS + tn * 16 + l16] = (short)__bfloat16_as_ushort(f2bf(p));
                }
                lsum[tm][r] += rs;
            }
        }
        // no barrier: Ps rows [wq, wq+32) are written and read by this wave only

        // PV: O[32 x 64] per wave
#pragma unroll
        for (int ks = 0; ks < 64; ks += 32) {
            bf16x8_t ap[2], bv[4];
#pragma unroll
            for (int tm = 0; tm < 2; ++tm)
                ap[tm] = *(const bf16x8_t*)&Ps[(wq + tm * 16 + l16) * PS + ks + quad * 8];
#pragma unroll
            for (int tn = 0; tn < 4; ++tn)
                bv[tn] = *(const bf16x8_t*)&Vt[(tn * 16 + l16) * VS + ks + quad * 8];
#pragma unroll
            for (int tm = 0; tm < 2; ++tm)
#pragma unroll
                for (int tn = 0; tn < 4; ++tn)
                    Oacc[tm][tn] = __builtin_amdgcn_mfma_f32_16x16x32_bf16(
                        ap[tm], bv[tn], Oacc[tm][tn], 0, 0, 0);
        }
    }

    // reduce row sums across 16 col-lanes, normalize, store
    float linv[2][4];
#pragma unroll
    for (int tm = 0; tm < 2; ++tm)
#pragma unroll
        for (int r = 0; r < 4; ++r) {
            float v = lsum[tm][r];
            v += __shfl_xor(v, 1, 64);
            v += __shfl_xor(v, 2, 64);
            v += __shfl_xor(v, 4, 64);
            v += __shfl_xor(v, 8, 64);
            linv[tm][r] = 1.f / v;
        }
    const int b = bh / H_, h = bh % H_;
#pragma unroll
    for (int tm = 0; tm < 2; ++tm) {
#pragma unroll
        for (int r = 0; r < 4; ++r) {
            int row = q0 + wq + tm * 16 + quad * 4 + r;
            size_t ob = ((size_t)b * S_ + row) * D_ + h * HD_;
#pragma unroll
            for (int tn = 0; tn < 4; ++tn)
                O[ob + tn * 16 + l16] = f2bf(Oacc[tm][tn][r] * linv[tm][r]);
        }
    }
}

// ---------------------------------------------------------------------------
extern "C" void kernel_launch(void* const* d_in, const int* in_sizes, int n_in,
                              void* d_out, int out_size, void* d_ws, size_t ws_size,
                              hipStream_t stream) {
    const float* x      = (const float*)d_in[0];
    const float* qkv_w  = (const float*)d_in[1];
    const float* qkv_b  = (const float*)d_in[2];
    const float* proj_w = (const float*)d_in[3];
    const float* proj_b = (const float*)d_in[4];
    float* out = (float*)d_out;

    unsigned short* q     = (unsigned short*)d_ws;
    unsigned short* k     = q + QKV_ELEMS;
    unsigned short* v     = k + QKV_ELEMS;
    unsigned short* slot4 = v + QKV_ELEMS;          // x_bf, then attn-out
    unsigned short* wq    = slot4 + QKV_ELEMS;
    unsigned short* wp    = wq + 2304 * 768;

    f2bf_kernel<<<(16384 * 768 / 4 + 255) / 256, 256, 0, stream>>>(x, slot4, 16384 * 768 / 4);
    f2bf_kernel<<<(2304 * 768 / 4 + 255) / 256, 256, 0, stream>>>(qkv_w, wq, 2304 * 768 / 4);
    f2bf_kernel<<<(768 * 768 / 4 + 255) / 256, 256, 0, stream>>>(proj_w, wp, 768 * 768 / 4);

    // 16384/256 = 64 m-blocks; qkv: 2304/256 = 9 n-blocks; proj: 768/256 = 3
    qkv_gemm_mfma<<<dim3(64 * 9), 512, 0, stream>>>(
        (const short*)slot4, (const short*)wq, qkv_b,
        (bf16*)q, (bf16*)k, (bf16*)v);

    attn_mfma<<<dim3(32 * 12 * 4), 256, 0, stream>>>(
        (const short*)q, (const short*)k, (const short*)v, (bf16*)slot4);

    proj_gemm_mfma<<<dim3(64 * 3), 512, 0, stream>>>(
        (const short*)slot4, (const short*)wp, proj_b, out);
}